// Round 1
// baseline (472.611 us; speedup 1.0000x reference)
//
#include <hip/hip_runtime.h>

// Problem constants (from reference)
#define N_NODES 100000
#define N_EDGES 1600000
#define D_FEAT  32

// One thread per (edge, feat). Lanes f=0..31 of a half-wave cover one edge's
// 32 contiguous floats -> coalesced pattern read + single-cacheline rel gather.
// Accumulate msg directly into d_out (zeroed first), degree into d_ws.
__global__ void sage_edge_kernel(const float* __restrict__ rel,
                                 const float* __restrict__ pattern,
                                 const int*   __restrict__ src,
                                 const int*   __restrict__ dst,
                                 float* __restrict__ sums,   // d_out, pre-zeroed
                                 float* __restrict__ deg) {  // d_ws,  pre-zeroed
    int i = blockIdx.x * blockDim.x + threadIdx.x;   // < E*32 = 51.2M, fits int
    if (i >= N_EDGES * D_FEAT) return;
    int e = i >> 5;        // edge index
    int f = i & 31;        // feature index
    int s = src[e];
    int d = dst[e];
    float m = rel[s * D_FEAT + f] * pattern[i];
    atomicAdd(&sums[d * D_FEAT + f], m);
    if (f == 0) atomicAdd(&deg[d], 1.0f);   // one degree count per edge
}

// out = sums / max(deg,1) + rel   (DGL mean semantics: zero-indegree stays 0)
__global__ void sage_node_kernel(const float* __restrict__ rel,
                                 const float* __restrict__ deg,
                                 float* __restrict__ out) {
    int i = blockIdx.x * blockDim.x + threadIdx.x;
    if (i >= N_NODES * D_FEAT) return;
    int n = i >> 5;
    out[i] = out[i] / fmaxf(deg[n], 1.0f) + rel[i];
}

extern "C" void kernel_launch(void* const* d_in, const int* in_sizes, int n_in,
                              void* d_out, int out_size, void* d_ws, size_t ws_size,
                              hipStream_t stream) {
    const float* rel     = (const float*)d_in[0];   // [N, 32] fp32
    const float* pattern = (const float*)d_in[1];   // [E, 32] fp32
    const int*   src     = (const int*)d_in[2];     // [E] (harness passes int32)
    const int*   dst     = (const int*)d_in[3];     // [E]
    float* out = (float*)d_out;                      // [N, 32] fp32
    float* deg = (float*)d_ws;                       // [N] fp32 scratch

    // d_out / d_ws are re-poisoned to 0xAA before every timed launch -> zero here.
    hipMemsetAsync(out, 0, sizeof(float) * N_NODES * D_FEAT, stream);
    hipMemsetAsync(deg, 0, sizeof(float) * N_NODES, stream);

    int edge_threads = N_EDGES * D_FEAT;
    sage_edge_kernel<<<(edge_threads + 255) / 256, 256, 0, stream>>>(
        rel, pattern, src, dst, out, deg);

    int node_threads = N_NODES * D_FEAT;
    sage_node_kernel<<<(node_threads + 255) / 256, 256, 0, stream>>>(
        rel, deg, out);
}